// Round 17
// baseline (153.108 us; speedup 1.0000x reference)
//
#include <hip/hip_runtime.h>

typedef unsigned short u16;
typedef __attribute__((ext_vector_type(8))) short short8;
typedef __attribute__((ext_vector_type(4))) float f32x4;
typedef __attribute__((ext_vector_type(4))) unsigned short us4;

#define MFMA(a,b,c) __builtin_amdgcn_mfma_f32_16x16x32_bf16(a,b,c,0,0,0)
#define LOG2E 1.44269504088896341f
#define FENCE asm volatile("" ::: "memory")

__device__ __forceinline__ u16 f2bf(float f) {
  unsigned u = __builtin_bit_cast(unsigned, f);
  return (u16)((u + 0x7FFFu + ((u >> 16) & 1u)) >> 16);
}
__device__ __forceinline__ float bf2f(u16 u) {
  return __builtin_bit_cast(float, (unsigned)u << 16);
}
__device__ __forceinline__ unsigned cvtpk(float a, float b) {
  unsigned r;
  asm("v_cvt_pk_bf16_f32 %0, %1, %2" : "=v"(r) : "v"(a), "v"(b));
  return r;
}
__device__ __forceinline__ float sigmoidf_(float x) { return 1.f / (1.f + __expf(-x)); }

__device__ __forceinline__ void gload16(const void* g, void* l) {
  __builtin_amdgcn_global_load_lds(
      (const __attribute__((address_space(1))) void*)g,
      (__attribute__((address_space(3))) void*)l, 16, 0, 0);
}

__device__ __forceinline__ void blockreduce2(float& a, float& b) {
  #pragma unroll
  for (int d = 1; d < 64; d <<= 1) { a += __shfl_xor(a, d); b += __shfl_xor(b, d); }
  __shared__ float red[8];
  int w = threadIdx.x >> 6, l = threadIdx.x & 63;
  if (l == 0) { red[w] = a; red[4 + w] = b; }
  __syncthreads();
  a = red[0] + red[1] + red[2] + red[3];
  b = red[4] + red[5] + red[6] + red[7];
}

// ---------------- FUSED: LN prep + weight convert ----------------
// blocks [0,4097): ln_prep; blocks [4097, 7841): cvt_weights
__global__ __launch_bounds__(256) void prep_fused(
    const float* __restrict__ x, const float* __restrict__ sc,
    const float* __restrict__ sc_ln_w, const float* __restrict__ mask,
    float* __restrict__ xn, u16* __restrict__ sc_bf, u16* __restrict__ scr_bf,
    float* __restrict__ mbv,
    const float* __restrict__ sw, const float* __restrict__ bw, const float* __restrict__ aw,
    const float* __restrict__ qw, const float* __restrict__ kw, const float* __restrict__ vw,
    const float* __restrict__ gw, const float* __restrict__ tw,
    u16* __restrict__ wsb, u16* __restrict__ waz, u16* __restrict__ wqkvg, u16* __restrict__ wt2)
{
  int bid = blockIdx.x, t = threadIdx.x;
  if (bid >= 4097) {
    long i = ((long)(bid - 4097) * 256 + t) * 4;
    const float* src; u16* dst;
    if      (i < 294912)  { src = sw + i;             dst = wsb + i; }
    else if (i < 589824)  { src = bw + (i - 294912);  dst = wsb + i; }
    else if (i < 884736)  { src = aw + (i - 589824);  dst = waz + (i - 589824); }
    else if (i < 1474560) { src = qw + (i - 884736);  dst = wqkvg + (i - 884736); }
    else if (i < 2064384) { src = kw + (i - 1474560); dst = wqkvg + (i - 884736); }
    else if (i < 2654208) { src = vw + (i - 2064384); dst = wqkvg + (i - 884736); }
    else if (i < 3244032) { src = gw + (i - 2654208); dst = wqkvg + (i - 884736); }
    else                  { src = tw + (i - 3244032); dst = wt2 + (i - 3244032); }
    f32x4 v = *(const f32x4*)src;
    us4 o = { f2bf(v[0]), f2bf(v[1]), f2bf(v[2]), f2bf(v[3]) };
    *(us4*)dst = o;
    return;
  }
  if (bid < 2048) {
    const float* row = x + (long)bid * 768;
    float v0 = row[t], v1 = row[t + 256], v2 = row[t + 512];
    float s = v0 + v1 + v2, sq = v0*v0 + v1*v1 + v2*v2;
    blockreduce2(s, sq);
    float mean = s * (1.f / 768.f);
    float var = sq * (1.f / 768.f) - mean * mean;
    float rs = rsqrtf(var + 1e-5f);
    float* orow = xn + (long)bid * 768;
    orow[t] = (v0 - mean) * rs; orow[t + 256] = (v1 - mean) * rs; orow[t + 512] = (v2 - mean) * rs;
  } else if (bid < 4096) {
    int r = bid - 2048;
    const float* row = sc + (long)r * 384;
    float v0 = row[t];
    float v1 = (t < 128) ? row[t + 256] : 0.f;
    float s = v0 + v1, sq = v0*v0 + v1*v1;
    blockreduce2(s, sq);
    float mean = s * (1.f / 384.f), var = sq * (1.f / 384.f) - mean * mean;
    float rs = rsqrtf(var + 1e-5f);
    sc_bf[r*384 + t]  = f2bf((v0 - mean) * rs * sc_ln_w[t]);
    scr_bf[r*384 + t] = f2bf(v0);
    if (t < 128) {
      sc_bf[r*384 + t + 256]  = f2bf((v1 - mean) * rs * sc_ln_w[t + 256]);
      scr_bf[r*384 + t + 256] = f2bf(v1);
    }
  } else {
    for (int i = t; i < 2048; i += 256) mbv[i] = 1e9f * (mask[i] - 1.f);
  }
}

// ---------------- FUSED: gemm1 (sc->Y1) + gemmYaz (scr->Yaz), 64x64 tiles ----------------
// grid (32, 36): y<24 -> Y1 = sc_bf @ Wsb^T (M=1536); y>=24 -> Yaz = scr_bf @ Waz^T (M=768)
__global__ __launch_bounds__(256) void gemm_pair64(
    const u16* __restrict__ X0, const u16* __restrict__ W0, float* __restrict__ Y0,
    const u16* __restrict__ X1, const u16* __restrict__ W1, float* __restrict__ Y1o)
{
  __shared__ u16 lA[2048];
  __shared__ u16 lB[2048];
  const int K = 384;
  const bool second = blockIdx.y >= 24;
  const u16* X = second ? X1 : X0;
  const u16* W = second ? W1 : W0;
  float* Y = second ? Y1o : Y0;
  const int M = second ? 768 : 1536;
  const int row0 = blockIdx.x << 6;
  const int col0 = (second ? (blockIdx.y - 24) : blockIdx.y) << 6;
  const int tid = threadIdx.x;
  const int w = tid >> 6, l = tid & 63;
  const int wr = (w >> 1) << 5, wc = (w & 1) << 5;
  const int g = l >> 4, r16 = l & 15;
  const int srow = w * 16 + (l >> 2);
  const int scol = (l & 3) * 8;
  f32x4 acc[2][2] = {};
  for (int k0 = 0; k0 < K; k0 += 32) {
    gload16(X + (long)(row0 + srow) * K + k0 + scol, &lA[w*512]);
    gload16(W + (long)(col0 + srow) * K + k0 + scol, &lB[w*512]);
    __syncthreads();
    short8 af[2], bw_[2];
    #pragma unroll
    for (int i = 0; i < 2; ++i) { af[i]  = *(const short8*)&lA[(wr + i*16 + r16)*32 + g*8]; }
    #pragma unroll
    for (int j = 0; j < 2; ++j) { bw_[j] = *(const short8*)&lB[(wc + j*16 + r16)*32 + g*8]; }
    #pragma unroll
    for (int i = 0; i < 2; ++i)
      #pragma unroll
      for (int j = 0; j < 2; ++j)
        acc[i][j] = MFMA(af[i], bw_[j], acc[i][j]);
    __syncthreads();
  }
  #pragma unroll
  for (int i = 0; i < 2; ++i) {
    #pragma unroll
    for (int j = 0; j < 2; ++j) {
      long rr = row0 + wr + i*16 + g*4;
      int cc = col0 + wc + j*16 + r16;
      #pragma unroll
      for (int r = 0; r < 4; ++r) { Y[(rr + r) * M + cc] = acc[i][j][r]; }
    }
  }
}

// ---------------- 64x64-tile t2 GEMM with fused azsig: out = azs * (X @ W^T) ----------------
__global__ __launch_bounds__(256) void gemm_az64(
    const u16* __restrict__ X, const u16* __restrict__ W,
    const float* __restrict__ azs, float* __restrict__ Y, int M, int K)
{
  __shared__ u16 lA[2048];
  __shared__ u16 lB[2048];
  const int row0 = blockIdx.x << 6;
  const int col0 = blockIdx.y << 6;
  const int tid = threadIdx.x;
  const int w = tid >> 6, l = tid & 63;
  const int wr = (w >> 1) << 5, wc = (w & 1) << 5;
  const int g = l >> 4, r16 = l & 15;
  const int srow = w * 16 + (l >> 2);
  const int scol = (l & 3) * 8;
  f32x4 acc[2][2] = {};
  for (int k0 = 0; k0 < K; k0 += 32) {
    gload16(X + (long)(row0 + srow) * K + k0 + scol, &lA[w*512]);
    gload16(W + (long)(col0 + srow) * K + k0 + scol, &lB[w*512]);
    __syncthreads();
    short8 af[2], bw_[2];
    #pragma unroll
    for (int i = 0; i < 2; ++i) { af[i]  = *(const short8*)&lA[(wr + i*16 + r16)*32 + g*8]; }
    #pragma unroll
    for (int j = 0; j < 2; ++j) { bw_[j] = *(const short8*)&lB[(wc + j*16 + r16)*32 + g*8]; }
    #pragma unroll
    for (int i = 0; i < 2; ++i)
      #pragma unroll
      for (int j = 0; j < 2; ++j)
        acc[i][j] = MFMA(af[i], bw_[j], acc[i][j]);
    __syncthreads();
  }
  #pragma unroll
  for (int i = 0; i < 2; ++i) {
    #pragma unroll
    for (int j = 0; j < 2; ++j) {
      long rr = row0 + wr + i*16 + g*4;
      int cc = col0 + wc + j*16 + r16;
      #pragma unroll
      for (int r = 0; r < 4; ++r) {
        Y[(rr + r) * M + cc] = acc[i][j][r] * azs[(rr + r) * M + cc];
      }
    }
  }
}

// ---------------- QKVG GEMM, 64x64 tile, fused pack + pad_init ----------------
// grid (32, 49): y<48 GEMM+pack; y==48 pad strip init (d=48..63 of qpad/kpad).
__global__ __launch_bounds__(256) void gemm_qkvg64(
    const u16* __restrict__ X, const u16* __restrict__ W,
    const float* __restrict__ q_b, const float* __restrict__ mbv,
    u16* __restrict__ qpad, u16* __restrict__ kpad,
    u16* __restrict__ vt, u16* __restrict__ gsig)
{
  if (blockIdx.y == 48) {
    int t0 = (blockIdx.x * 256 + threadIdx.x) * 4;  // 8192 threads x 4 strips = 32768
    us4 z = {0, 0, 0, 0};
    #pragma unroll
    for (int s = 0; s < 4; ++s) {
      int t = t0 + s;
      int n = t & 2047;
      long base = (long)t * 64 + 48;
      us4 q0 = { f2bf(1.0f), 0, 0, 0 };
      us4 k0 = { f2bf(mbv[n]), 0, 0, 0 };
      *(us4*)(qpad + base) = q0;  *(us4*)(qpad + base + 4) = z;
      *(us4*)(qpad + base + 8) = z; *(us4*)(qpad + base + 12) = z;
      *(us4*)(kpad + base) = k0;  *(us4*)(kpad + base + 4) = z;
      *(us4*)(kpad + base + 8) = z; *(us4*)(kpad + base + 12) = z;
    }
    return;
  }
  __shared__ u16 lA[2048];
  __shared__ u16 lB[2048];
  const int K = 768;
  const int row0 = blockIdx.x << 6;
  const int col0 = blockIdx.y << 6;
  const int tid = threadIdx.x;
  const int w = tid >> 6, l = tid & 63;
  const int wr = (w >> 1) << 5, wc = (w & 1) << 5;
  const int g = l >> 4, r16 = l & 15;
  const int srow = w * 16 + (l >> 2);
  const int scol = (l & 3) * 8;
  f32x4 acc[2][2] = {};
  for (int k0 = 0; k0 < K; k0 += 32) {
    gload16(X + (long)(row0 + srow) * K + k0 + scol, &lA[w*512]);
    gload16(W + (long)(col0 + srow) * K + k0 + scol, &lB[w*512]);
    __syncthreads();
    short8 af[2], bw_[2];
    #pragma unroll
    for (int i = 0; i < 2; ++i) { af[i]  = *(const short8*)&lA[(wr + i*16 + r16)*32 + g*8]; }
    #pragma unroll
    for (int j = 0; j < 2; ++j) { bw_[j] = *(const short8*)&lB[(wc + j*16 + r16)*32 + g*8]; }
    #pragma unroll
    for (int i = 0; i < 2; ++i)
      #pragma unroll
      for (int j = 0; j < 2; ++j)
        acc[i][j] = MFMA(af[i], bw_[j], acc[i][j]);
    __syncthreads();
  }
  const int sec = (col0 >= 2304) ? 3 : (col0 >= 1536) ? 2 : (col0 >= 768) ? 1 : 0;
  #pragma unroll
  for (int i = 0; i < 2; ++i) {
    #pragma unroll
    for (int j = 0; j < 2; ++j) {
      int rr = row0 + wr + i*16 + g*4;
      int cc = col0 + wc + j*16 + r16;
      if (sec == 0) {
        int m = cc, h = m / 48, d = m - h * 48;
        float qb = q_b[m];
        #pragma unroll
        for (int r = 0; r < 4; ++r)
          qpad[((long)h*2048 + rr + r)*64 + d] =
              f2bf((acc[i][j][r] + qb) * 0.14433756729740643f);
      } else if (sec == 1) {
        int m = cc - 768, h = m / 48, d = m - h * 48;
        #pragma unroll
        for (int r = 0; r < 4; ++r)
          kpad[((long)h*2048 + rr + r)*64 + d] = f2bf(acc[i][j][r]);
      } else if (sec == 2) {
        int m = cc - 1536, h = m / 48, d = m - h * 48;
        us4 o = { f2bf(acc[i][j][0]), f2bf(acc[i][j][1]),
                  f2bf(acc[i][j][2]), f2bf(acc[i][j][3]) };
        *(us4*)(vt + ((long)h*48 + d)*2048 + rr) = o;
      } else {
        int m = cc - 2304;
        #pragma unroll
        for (int r = 0; r < 4; ++r)
          gsig[(long)(rr + r)*768 + m] = f2bf(sigmoidf_(acc[i][j][r]));
      }
    }
  }
}

// ---------------- adaLN epilogue ----------------
__global__ __launch_bounds__(256) void ada_kernel(
    const float* __restrict__ Y1, const float* __restrict__ Yaz,
    const float* __restrict__ xn, const float* __restrict__ scale_b,
    const float* __restrict__ az_b, u16* __restrict__ xm, float* __restrict__ azsig)
{
  long e = ((long)blockIdx.x * 256 + threadIdx.x) * 4;
  int n = (int)(e / 768), c = (int)(e % 768);
  f32x4 ys = *(const f32x4*)(Y1 + (long)n*1536 + c);
  f32x4 yb = *(const f32x4*)(Y1 + (long)n*1536 + 768 + c);
  f32x4 xv = *(const f32x4*)(xn + e);
  f32x4 sb = *(const f32x4*)(scale_b + c);
  f32x4 ya = *(const f32x4*)(Yaz + e);
  f32x4 ab = *(const f32x4*)(az_b + c);
  us4 o; f32x4 az;
  #pragma unroll
  for (int k = 0; k < 4; ++k) {
    o[k] = f2bf(sigmoidf_(ys[k] + sb[k]) * xv[k] + yb[k]);
    az[k] = sigmoidf_(ya[k] + ab[k]);
  }
  *(us4*)(xm + e) = o;
  *(f32x4*)(azsig + e) = az;
}

// ---------------- attention (exact R12/R14 structure: best known) ----------------
__global__ __launch_bounds__(256, 3) void attn_kernel(
    const u16* __restrict__ qpad, const u16* __restrict__ kpad,
    const u16* __restrict__ vt, const float* __restrict__ pair,
    const u16* __restrict__ gsig, u16* __restrict__ wg)
{
  __shared__ __align__(16) char smem[36864];  // K 2x8K @0 | V 2x6K @16384 | P 4x2K @28672
  const int bid = blockIdx.x;
  const int h = ((bid & 7) << 1) | ((bid >> 3) & 1);  // 2 heads per XCD
  const int qb = bid >> 4;
  const int tid = threadIdx.x, w = tid >> 6, l = tid & 63;
  const int g = l >> 4, q = l & 15;
  const int qrow = qb * 64 + w * 16 + q;

  const u16* qbase = qpad + ((long)h * 2048 + qrow) * 64;
  short8 qf0 = *(const short8*)(qbase + g * 8);
  short8 qf1 = *(const short8*)(qbase + 32 + g * 8);

  const float* prow = pair + ((long)h * 2048 + qrow) * 2048;
  const u16*   kgl  = kpad + (long)h * 2048 * 64;
  const u16*   vgl  = vt   + (long)h * 48 * 2048;
  const int sr8 = l >> 3, sc8 = l & 7;
  unsigned* pl = (unsigned*)(smem + 28672) + w*512 + q*32;
  const int sx = (q & 7) << 2;

  f32x4 prA[4], prB[4];

  #define STAGE_PR(KT, BUF) do {                                                  \
    _Pragma("unroll")                                                             \
    for (int mf_ = 0; mf_ < 4; ++mf_)                                             \
      BUF[mf_] = __builtin_nontemporal_load(                                      \
          (const f32x4*)(prow + (long)(KT)*64 + mf_*16 + g*4));                   \
  } while (0)

  #define STAGE_KV(KT, BI) do {                                                   \
    char* kd = smem + (BI)*8192 + w*2048;                                          \
    _Pragma("unroll")                                                              \
    for (int i_ = 0; i_ < 2; ++i_) {                                               \
      int row_ = i_*8 + sr8;                                                       \
      gload16(kgl + (long)((KT)*64 + w*16 + row_)*64 + ((sc8 ^ (row_&7)) << 3),    \
              kd + i_*1024);                                                       \
    }                                                                              \
    if (w > 0) {                                                                   \
      char* vd = smem + 16384 + (BI)*6144 + (w-1)*2048;                            \
      _Pragma("unroll")                                                            \
      for (int i_ = 0; i_ < 2; ++i_) {                                             \
        int row_ = i_*8 + sr8;                                                     \
        gload16(vgl + (long)((w-1)*16 + row_)*2048 + (KT)*64 +                     \
                ((sc8 ^ (row_&7)) << 3), vd + i_*1024);                            \
      }                                                                            \
    }                                                                              \
  } while (0)

  STAGE_PR(0, prA); STAGE_KV(0, 0);
  STAGE_PR(1, prB); STAGE_KV(1, 1);

  float m = -1e30f, ssum = 0.f;
  f32x4 o0 = {0,0,0,0}, o1 = {0,0,0,0}, o2 = {0,0,0,0};

  #define BODY(T, PRBUF, PAR) do {                                                \
    if ((T) == 31)   { asm volatile("s_waitcnt vmcnt(0)" ::: "memory"); }          \
    else if (w == 0) { asm volatile("s_waitcnt vmcnt(6)" ::: "memory"); }          \
    else             { asm volatile("s_waitcnt vmcnt(8)" ::: "memory"); }          \
    __builtin_amdgcn_s_barrier();                                                  \
    FENCE;                                                                         \
    const char* kb = smem + (PAR)*8192;                                            \
    const char* vb = smem + 16384 + (PAR)*6144;                                    \
    f32x4 s[4];                                                                    \
    _Pragma("unroll")                                                              \
    for (int mf = 0; mf < 4; ++mf) {                                               \
      const int kr = mf*16 + q;                                                    \
      short8 ka = *(const short8*)(kb + kr*128 + ((g       ^ (q&7)) << 4));        \
      short8 kc = *(const short8*)(kb + kr*128 + (((g + 4) ^ (q&7)) << 4));        \
      s[mf] = MFMA(ka, qf0, PRBUF[mf]);                                            \
      s[mf] = MFMA(kc, qf1, s[mf]);                                                \
    }                                                                              \
    float tmax = -3e38f;                                                           \
    _Pragma("unroll")                                                              \
    for (int mf = 0; mf < 4; ++mf)                                                 \
      tmax = fmaxf(tmax, fmaxf(fmaxf(s[mf][0], s[mf][1]), fmaxf(s[mf][2], s[mf][3])));\
    tmax = fmaxf(tmax, __shfl_xor(tmax, 16));                                      \
    tmax = fmaxf(tmax, __shfl_xor(tmax, 32));                                      \
    float mnew = fmaxf(m, tmax);                                                   \
    float alpha = exp2f((m - mnew) * LOG2E);                                       \
    m = mnew;                                                                      \
    float mL = mnew * LOG2E;                                                       \
    float psum = 0.f;                                                              \
    unsigned pk0[4], pk1[4];                                                       \
    _Pragma("unroll")                                                              \
    for (int mf = 0; mf < 4; ++mf) {                                               \
      float p0 = exp2f(fmaf(s[mf][0], LOG2E, -mL));                                \
      float p1 = exp2f(fmaf(s[mf][1], LOG2E, -mL));                                \
      float p2 = exp2f(fmaf(s[mf][2], LOG2E, -mL));                                \
      float p3 = exp2f(fmaf(s[mf][3], LOG2E, -mL));                                \
      psum += (p0 + p1) + (p2 + p3);                                               \
      pk0[mf] = cvtpk(p0, p1);                                                     \
      pk1[mf] = cvtpk(p2, p3);                                                     \
    }                                                                              \
    ssum = ssum * alpha + psum;                                                    \
    o0 *= alpha; o1 *= alpha; o2 *= alpha;                                         \
    _Pragma("unroll")                                                              \
    for (int mf = 0; mf < 4; ++mf) {                                               \
      uint2 pv_; pv_.x = pk0[mf]; pv_.y = pk1[mf];                                 \
      *(uint2*)(pl + ((mf*8 + g*2) ^ sx)) = pv_;                                   \
    }                                                                              \
    asm volatile("s_waitcnt lgkmcnt(0)" ::: "memory");                             \
    __builtin_amdgcn_sched_barrier(0);                                             \
    _Pragma("unroll")                                                              \
    for (int ks = 0; ks < 2; ++ks) {                                               \
      union { uint4 u4; short8 v; } pf;                                            \
      pf.u4 = *(const uint4*)(pl + ((ks*16 + g*4) ^ sx));                          \
      const int vc = ((ks*4 + g) ^ (q & 7)) << 4;                                  \
      short8 v0 = *(const short8*)(vb + (q)*128      + vc);                        \
      short8 v1 = *(const short8*)(vb + (16 + q)*128 + vc);                        \
      short8 v2 = *(const short8*)(vb + (32 + q)*128 + vc);                        \
      o0 = MFMA(v0, pf.v, o0);                                                     \
      o1 = MFMA(v1, pf.v, o1);                                                     \
      o2 = MFMA(v2, pf.v, o2);                                                     \
    }                                                                              \
    FENCE;                                                                         \
    __builtin_amdgcn_s_barrier();                                                  \
    FENCE;                                                                         \
    if ((T) < 30) { STAGE_PR((T)+2, PRBUF); STAGE_KV((T)+2, PAR); }                \
    __builtin_amdgcn_sched_barrier(0);                                             \
  } while (0)

  for (int t = 0; t < 32; t += 2) {
    BODY(t,     prA, 0);
    BODY(t + 1, prB, 1);
  }
  #undef BODY
  #undef STAGE_PR
  #undef STAGE_KV

  ssum += __shfl_xor(ssum, 16);
  ssum += __shfl_xor(ssum, 32);
  float rinv = 1.f / ssum;
  const long nbase = (long)qrow * 768 + h * 48;
  #pragma unroll
  for (int r = 0; r < 3; ++r) {
    f32x4 ov = (r == 0) ? o0 : ((r == 1) ? o1 : o2);
    int c = r * 16 + g * 4;
    us4 gs = *(const us4*)(gsig + nbase + c);
    us4 ou;
    #pragma unroll
    for (int j = 0; j < 4; ++j) ou[j] = f2bf(ov[j] * rinv * bf2f(gs[j]));
    *(us4*)(wg + nbase + c) = ou;
  }
}

extern "C" void kernel_launch(void* const* d_in, const int* in_sizes, int n_in,
                              void* d_out, int out_size, void* d_ws, size_t ws_size,
                              hipStream_t stream) {
  const float* x       = (const float*)d_in[0];
  const float* mask    = (const float*)d_in[1];
  const float* pair    = (const float*)d_in[2];
  const float* sc      = (const float*)d_in[3];
  const float* q_w     = (const float*)d_in[4];
  const float* q_b     = (const float*)d_in[5];
  const float* k_w     = (const float*)d_in[6];
  const float* v_w     = (const float*)d_in[7];
  const float* g_w     = (const float*)d_in[8];
  const float* slw     = (const float*)d_in[9];
  const float* scale_w = (const float*)d_in[10];
  const float* scale_b = (const float*)d_in[11];
  const float* bias_w  = (const float*)d_in[12];
  const float* t2_w    = (const float*)d_in[13];
  const float* az_w    = (const float*)d_in[14];
  const float* az_b    = (const float*)d_in[15];
  float* out = (float*)d_out;
  char* ws = (char*)d_ws;

  u16*   Wsb   = (u16*)  (ws + 0);
  u16*   Waz   = (u16*)  (ws + 1179648);
  u16*   Wqkvg = (u16*)  (ws + 1769472);
  u16*   Wt2   = (u16*)  (ws + 6488064);
  float* xn    = (float*)(ws + 7667712);
  u16*   sc_bf = (u16*)  (ws + 13959168);
  u16*   scr_bf= (u16*)  (ws + 15532032);
  u16*   wg    = (u16*)  (ws + 13959168);   // reuse (sc dead after gemm_pair/ada)
  float* mb    = (float*)(ws + 17104896);
  float* Y1    = (float*)(ws + 17113088);
  u16*   qpad  = (u16*)  (ws + 17113088);   // reuse Y1 (dead after ada)
  u16*   kpad  = (u16*)  (ws + 21307392);
  float* Yaz   = (float*)(ws + 29696000);
  u16*   xm    = (u16*)  (ws + 35987456);
  float* azsig = (float*)(ws + 39133184);
  u16*   vt    = (u16*)  (ws + 70590464);
  u16*   gsig  = (u16*)  (ws + 73736192);

  prep_fused<<<7841, 256, 0, stream>>>(x, sc, slw, mask, xn, sc_bf, scr_bf, mb,
                                       scale_w, bias_w, az_w, q_w, k_w, v_w, g_w, t2_w,
                                       Wsb, Waz, Wqkvg, Wt2);
  gemm_pair64<<<dim3(32, 36), 256, 0, stream>>>(sc_bf, Wsb, Y1, scr_bf, Waz, Yaz);
  ada_kernel<<<1536, 256, 0, stream>>>(Y1, Yaz, xn, scale_b, az_b, xm, azsig);
  gemm_qkvg64<<<dim3(32, 49), 256, 0, stream>>>(xm, Wqkvg, q_b, mb, qpad, kpad, vt, gsig);
  attn_kernel<<<512, 256, 0, stream>>>(qpad, kpad, vt, pair, gsig, wg);
  gemm_az64<<<dim3(32, 12), 256, 0, stream>>>(wg, Wt2, azsig, out, 768, 768);
}

// Round 18
// 152.939 us; speedup vs baseline: 1.0011x; 1.0011x over previous
//
#include <hip/hip_runtime.h>

typedef unsigned short u16;
typedef __attribute__((ext_vector_type(8))) short short8;
typedef __attribute__((ext_vector_type(4))) float f32x4;
typedef __attribute__((ext_vector_type(4))) unsigned short us4;

#define MFMA(a,b,c) __builtin_amdgcn_mfma_f32_16x16x32_bf16(a,b,c,0,0,0)
#define LOG2E 1.44269504088896341f
#define FENCE asm volatile("" ::: "memory")

__device__ __forceinline__ u16 f2bf(float f) {
  unsigned u = __builtin_bit_cast(unsigned, f);
  return (u16)((u + 0x7FFFu + ((u >> 16) & 1u)) >> 16);
}
__device__ __forceinline__ float bf2f(u16 u) {
  return __builtin_bit_cast(float, (unsigned)u << 16);
}
__device__ __forceinline__ unsigned cvtpk(float a, float b) {
  unsigned r;
  asm("v_cvt_pk_bf16_f32 %0, %1, %2" : "=v"(r) : "v"(a), "v"(b));
  return r;
}
__device__ __forceinline__ float sigmoidf_(float x) { return 1.f / (1.f + __expf(-x)); }

__device__ __forceinline__ void gload16(const void* g, void* l) {
  __builtin_amdgcn_global_load_lds(
      (const __attribute__((address_space(1))) void*)g,
      (__attribute__((address_space(3))) void*)l, 16, 0, 0);
}

__device__ __forceinline__ void blockreduce2(float& a, float& b) {
  #pragma unroll
  for (int d = 1; d < 64; d <<= 1) { a += __shfl_xor(a, d); b += __shfl_xor(b, d); }
  __shared__ float red[8];
  int w = threadIdx.x >> 6, l = threadIdx.x & 63;
  if (l == 0) { red[w] = a; red[4 + w] = b; }
  __syncthreads();
  a = red[0] + red[1] + red[2] + red[3];
  b = red[4] + red[5] + red[6] + red[7];
}

// ---------------- FUSED: LN prep + weight convert ----------------
// blocks [0,4097): ln_prep; blocks [4097, 7841): cvt_weights
__global__ __launch_bounds__(256) void prep_fused(
    const float* __restrict__ x, const float* __restrict__ sc,
    const float* __restrict__ sc_ln_w, const float* __restrict__ mask,
    float* __restrict__ xn, u16* __restrict__ sc_bf, u16* __restrict__ scr_bf,
    float* __restrict__ mbv,
    const float* __restrict__ sw, const float* __restrict__ bw, const float* __restrict__ aw,
    const float* __restrict__ qw, const float* __restrict__ kw, const float* __restrict__ vw,
    const float* __restrict__ gw, const float* __restrict__ tw,
    u16* __restrict__ wsb, u16* __restrict__ waz, u16* __restrict__ wqkvg, u16* __restrict__ wt2)
{
  int bid = blockIdx.x, t = threadIdx.x;
  if (bid >= 4097) {
    long i = ((long)(bid - 4097) * 256 + t) * 4;
    const float* src; u16* dst;
    if      (i < 294912)  { src = sw + i;             dst = wsb + i; }
    else if (i < 589824)  { src = bw + (i - 294912);  dst = wsb + i; }
    else if (i < 884736)  { src = aw + (i - 589824);  dst = waz + (i - 589824); }
    else if (i < 1474560) { src = qw + (i - 884736);  dst = wqkvg + (i - 884736); }
    else if (i < 2064384) { src = kw + (i - 1474560); dst = wqkvg + (i - 884736); }
    else if (i < 2654208) { src = vw + (i - 2064384); dst = wqkvg + (i - 884736); }
    else if (i < 3244032) { src = gw + (i - 2654208); dst = wqkvg + (i - 884736); }
    else                  { src = tw + (i - 3244032); dst = wt2 + (i - 3244032); }
    f32x4 v = *(const f32x4*)src;
    us4 o = { f2bf(v[0]), f2bf(v[1]), f2bf(v[2]), f2bf(v[3]) };
    *(us4*)dst = o;
    return;
  }
  if (bid < 2048) {
    const float* row = x + (long)bid * 768;
    float v0 = row[t], v1 = row[t + 256], v2 = row[t + 512];
    float s = v0 + v1 + v2, sq = v0*v0 + v1*v1 + v2*v2;
    blockreduce2(s, sq);
    float mean = s * (1.f / 768.f);
    float var = sq * (1.f / 768.f) - mean * mean;
    float rs = rsqrtf(var + 1e-5f);
    float* orow = xn + (long)bid * 768;
    orow[t] = (v0 - mean) * rs; orow[t + 256] = (v1 - mean) * rs; orow[t + 512] = (v2 - mean) * rs;
  } else if (bid < 4096) {
    int r = bid - 2048;
    const float* row = sc + (long)r * 384;
    float v0 = row[t];
    float v1 = (t < 128) ? row[t + 256] : 0.f;
    float s = v0 + v1, sq = v0*v0 + v1*v1;
    blockreduce2(s, sq);
    float mean = s * (1.f / 384.f), var = sq * (1.f / 384.f) - mean * mean;
    float rs = rsqrtf(var + 1e-5f);
    sc_bf[r*384 + t]  = f2bf((v0 - mean) * rs * sc_ln_w[t]);
    scr_bf[r*384 + t] = f2bf(v0);
    if (t < 128) {
      sc_bf[r*384 + t + 256]  = f2bf((v1 - mean) * rs * sc_ln_w[t + 256]);
      scr_bf[r*384 + t + 256] = f2bf(v1);
    }
  } else {
    for (int i = t; i < 2048; i += 256) mbv[i] = 1e9f * (mask[i] - 1.f);
  }
}

// ---------------- FUSED: gemm1 (sc->Y1) + gemmYaz (scr->Yaz), 64x64 tiles ----------------
// grid (32, 36): y<24 -> Y1 = sc_bf @ Wsb^T (M=1536); y>=24 -> Yaz = scr_bf @ Waz^T (M=768)
__global__ __launch_bounds__(256) void gemm_pair64(
    const u16* __restrict__ X0, const u16* __restrict__ W0, float* __restrict__ Y0,
    const u16* __restrict__ X1, const u16* __restrict__ W1, float* __restrict__ Y1o)
{
  __shared__ u16 lA[2048];
  __shared__ u16 lB[2048];
  const int K = 384;
  const bool second = blockIdx.y >= 24;
  const u16* X = second ? X1 : X0;
  const u16* W = second ? W1 : W0;
  float* Y = second ? Y1o : Y0;
  const int M = second ? 768 : 1536;
  const int row0 = blockIdx.x << 6;
  const int col0 = (second ? (blockIdx.y - 24) : blockIdx.y) << 6;
  const int tid = threadIdx.x;
  const int w = tid >> 6, l = tid & 63;
  const int wr = (w >> 1) << 5, wc = (w & 1) << 5;
  const int g = l >> 4, r16 = l & 15;
  const int srow = w * 16 + (l >> 2);
  const int scol = (l & 3) * 8;
  f32x4 acc[2][2] = {};
  for (int k0 = 0; k0 < K; k0 += 32) {
    gload16(X + (long)(row0 + srow) * K + k0 + scol, &lA[w*512]);
    gload16(W + (long)(col0 + srow) * K + k0 + scol, &lB[w*512]);
    __syncthreads();
    short8 af[2], bw_[2];
    #pragma unroll
    for (int i = 0; i < 2; ++i) { af[i]  = *(const short8*)&lA[(wr + i*16 + r16)*32 + g*8]; }
    #pragma unroll
    for (int j = 0; j < 2; ++j) { bw_[j] = *(const short8*)&lB[(wc + j*16 + r16)*32 + g*8]; }
    #pragma unroll
    for (int i = 0; i < 2; ++i)
      #pragma unroll
      for (int j = 0; j < 2; ++j)
        acc[i][j] = MFMA(af[i], bw_[j], acc[i][j]);
    __syncthreads();
  }
  #pragma unroll
  for (int i = 0; i < 2; ++i) {
    #pragma unroll
    for (int j = 0; j < 2; ++j) {
      long rr = row0 + wr + i*16 + g*4;
      int cc = col0 + wc + j*16 + r16;
      #pragma unroll
      for (int r = 0; r < 4; ++r) { Y[(rr + r) * M + cc] = acc[i][j][r]; }
    }
  }
}

// ---------------- 64x64-tile t2 GEMM with fused azsig: out = azs * (X @ W^T) ----------------
__global__ __launch_bounds__(256) void gemm_az64(
    const u16* __restrict__ X, const u16* __restrict__ W,
    const float* __restrict__ azs, float* __restrict__ Y, int M, int K)
{
  __shared__ u16 lA[2048];
  __shared__ u16 lB[2048];
  const int row0 = blockIdx.x << 6;
  const int col0 = blockIdx.y << 6;
  const int tid = threadIdx.x;
  const int w = tid >> 6, l = tid & 63;
  const int wr = (w >> 1) << 5, wc = (w & 1) << 5;
  const int g = l >> 4, r16 = l & 15;
  const int srow = w * 16 + (l >> 2);
  const int scol = (l & 3) * 8;
  f32x4 acc[2][2] = {};
  for (int k0 = 0; k0 < K; k0 += 32) {
    gload16(X + (long)(row0 + srow) * K + k0 + scol, &lA[w*512]);
    gload16(W + (long)(col0 + srow) * K + k0 + scol, &lB[w*512]);
    __syncthreads();
    short8 af[2], bw_[2];
    #pragma unroll
    for (int i = 0; i < 2; ++i) { af[i]  = *(const short8*)&lA[(wr + i*16 + r16)*32 + g*8]; }
    #pragma unroll
    for (int j = 0; j < 2; ++j) { bw_[j] = *(const short8*)&lB[(wc + j*16 + r16)*32 + g*8]; }
    #pragma unroll
    for (int i = 0; i < 2; ++i)
      #pragma unroll
      for (int j = 0; j < 2; ++j)
        acc[i][j] = MFMA(af[i], bw_[j], acc[i][j]);
    __syncthreads();
  }
  #pragma unroll
  for (int i = 0; i < 2; ++i) {
    #pragma unroll
    for (int j = 0; j < 2; ++j) {
      long rr = row0 + wr + i*16 + g*4;
      int cc = col0 + wc + j*16 + r16;
      #pragma unroll
      for (int r = 0; r < 4; ++r) {
        Y[(rr + r) * M + cc] = acc[i][j][r] * azs[(rr + r) * M + cc];
      }
    }
  }
}

// ---------------- QKVG GEMM, 64x64 tile, fused pack + pad_init ----------------
// grid (32, 49): y<48 GEMM+pack; y==48 pad strip init (d=48..63 of qpad/kpad).
__global__ __launch_bounds__(256) void gemm_qkvg64(
    const u16* __restrict__ X, const u16* __restrict__ W,
    const float* __restrict__ q_b, const float* __restrict__ mbv,
    u16* __restrict__ qpad, u16* __restrict__ kpad,
    u16* __restrict__ vt, u16* __restrict__ gsig)
{
  if (blockIdx.y == 48) {
    int t0 = (blockIdx.x * 256 + threadIdx.x) * 4;  // 8192 threads x 4 strips = 32768
    us4 z = {0, 0, 0, 0};
    #pragma unroll
    for (int s = 0; s < 4; ++s) {
      int t = t0 + s;
      int n = t & 2047;
      long base = (long)t * 64 + 48;
      us4 q0 = { f2bf(1.0f), 0, 0, 0 };
      us4 k0 = { f2bf(mbv[n]), 0, 0, 0 };
      *(us4*)(qpad + base) = q0;  *(us4*)(qpad + base + 4) = z;
      *(us4*)(qpad + base + 8) = z; *(us4*)(qpad + base + 12) = z;
      *(us4*)(kpad + base) = k0;  *(us4*)(kpad + base + 4) = z;
      *(us4*)(kpad + base + 8) = z; *(us4*)(kpad + base + 12) = z;
    }
    return;
  }
  __shared__ u16 lA[2048];
  __shared__ u16 lB[2048];
  const int K = 768;
  const int row0 = blockIdx.x << 6;
  const int col0 = blockIdx.y << 6;
  const int tid = threadIdx.x;
  const int w = tid >> 6, l = tid & 63;
  const int wr = (w >> 1) << 5, wc = (w & 1) << 5;
  const int g = l >> 4, r16 = l & 15;
  const int srow = w * 16 + (l >> 2);
  const int scol = (l & 3) * 8;
  f32x4 acc[2][2] = {};
  for (int k0 = 0; k0 < K; k0 += 32) {
    gload16(X + (long)(row0 + srow) * K + k0 + scol, &lA[w*512]);
    gload16(W + (long)(col0 + srow) * K + k0 + scol, &lB[w*512]);
    __syncthreads();
    short8 af[2], bw_[2];
    #pragma unroll
    for (int i = 0; i < 2; ++i) { af[i]  = *(const short8*)&lA[(wr + i*16 + r16)*32 + g*8]; }
    #pragma unroll
    for (int j = 0; j < 2; ++j) { bw_[j] = *(const short8*)&lB[(wc + j*16 + r16)*32 + g*8]; }
    #pragma unroll
    for (int i = 0; i < 2; ++i)
      #pragma unroll
      for (int j = 0; j < 2; ++j)
        acc[i][j] = MFMA(af[i], bw_[j], acc[i][j]);
    __syncthreads();
  }
  const int sec = (col0 >= 2304) ? 3 : (col0 >= 1536) ? 2 : (col0 >= 768) ? 1 : 0;
  #pragma unroll
  for (int i = 0; i < 2; ++i) {
    #pragma unroll
    for (int j = 0; j < 2; ++j) {
      int rr = row0 + wr + i*16 + g*4;
      int cc = col0 + wc + j*16 + r16;
      if (sec == 0) {
        int m = cc, h = m / 48, d = m - h * 48;
        float qb = q_b[m];
        #pragma unroll
        for (int r = 0; r < 4; ++r)
          qpad[((long)h*2048 + rr + r)*64 + d] =
              f2bf((acc[i][j][r] + qb) * 0.14433756729740643f);
      } else if (sec == 1) {
        int m = cc - 768, h = m / 48, d = m - h * 48;
        #pragma unroll
        for (int r = 0; r < 4; ++r)
          kpad[((long)h*2048 + rr + r)*64 + d] = f2bf(acc[i][j][r]);
      } else if (sec == 2) {
        int m = cc - 1536, h = m / 48, d = m - h * 48;
        us4 o = { f2bf(acc[i][j][0]), f2bf(acc[i][j][1]),
                  f2bf(acc[i][j][2]), f2bf(acc[i][j][3]) };
        *(us4*)(vt + ((long)h*48 + d)*2048 + rr) = o;
      } else {
        int m = cc - 2304;
        #pragma unroll
        for (int r = 0; r < 4; ++r)
          gsig[(long)(rr + r)*768 + m] = f2bf(sigmoidf_(acc[i][j][r]));
      }
    }
  }
}

// ---------------- adaLN epilogue ----------------
__global__ __launch_bounds__(256) void ada_kernel(
    const float* __restrict__ Y1, const float* __restrict__ Yaz,
    const float* __restrict__ xn, const float* __restrict__ scale_b,
    const float* __restrict__ az_b, u16* __restrict__ xm, float* __restrict__ azsig)
{
  long e = ((long)blockIdx.x * 256 + threadIdx.x) * 4;
  int n = (int)(e / 768), c = (int)(e % 768);
  f32x4 ys = *(const f32x4*)(Y1 + (long)n*1536 + c);
  f32x4 yb = *(const f32x4*)(Y1 + (long)n*1536 + 768 + c);
  f32x4 xv = *(const f32x4*)(xn + e);
  f32x4 sb = *(const f32x4*)(scale_b + c);
  f32x4 ya = *(const f32x4*)(Yaz + e);
  f32x4 ab = *(const f32x4*)(az_b + c);
  us4 o; f32x4 az;
  #pragma unroll
  for (int k = 0; k < 4; ++k) {
    o[k] = f2bf(sigmoidf_(ys[k] + sb[k]) * xv[k] + yb[k]);
    az[k] = sigmoidf_(ya[k] + ab[k]);
  }
  *(us4*)(xm + e) = o;
  *(f32x4*)(azsig + e) = az;
}

// ---------------- attention (exact R12/R14 structure: best known) ----------------
__global__ __launch_bounds__(256, 3) void attn_kernel(
    const u16* __restrict__ qpad, const u16* __restrict__ kpad,
    const u16* __restrict__ vt, const float* __restrict__ pair,
    const u16* __restrict__ gsig, u16* __restrict__ wg)
{
  __shared__ __align__(16) char smem[36864];  // K 2x8K @0 | V 2x6K @16384 | P 4x2K @28672
  const int bid = blockIdx.x;
  const int h = ((bid & 7) << 1) | ((bid >> 3) & 1);  // 2 heads per XCD
  const int qb = bid >> 4;
  const int tid = threadIdx.x, w = tid >> 6, l = tid & 63;
  const int g = l >> 4, q = l & 15;
  const int qrow = qb * 64 + w * 16 + q;

  const u16* qbase = qpad + ((long)h * 2048 + qrow) * 64;
  short8 qf0 = *(const short8*)(qbase + g * 8);
  short8 qf1 = *(const short8*)(qbase + 32 + g * 8);

  const float* prow = pair + ((long)h * 2048 + qrow) * 2048;
  const u16*   kgl  = kpad + (long)h * 2048 * 64;
  const u16*   vgl  = vt   + (long)h * 48 * 2048;
  const int sr8 = l >> 3, sc8 = l & 7;
  unsigned* pl = (unsigned*)(smem + 28672) + w*512 + q*32;
  const int sx = (q & 7) << 2;

  f32x4 prA[4], prB[4];

  #define STAGE_PR(KT, BUF) do {                                                  \
    _Pragma("unroll")                                                             \
    for (int mf_ = 0; mf_ < 4; ++mf_)                                             \
      BUF[mf_] = __builtin_nontemporal_load(                                      \
          (const f32x4*)(prow + (long)(KT)*64 + mf_*16 + g*4));                   \
  } while (0)

  #define STAGE_KV(KT, BI) do {                                                   \
    char* kd = smem + (BI)*8192 + w*2048;                                          \
    _Pragma("unroll")                                                              \
    for (int i_ = 0; i_ < 2; ++i_) {                                               \
      int row_ = i_*8 + sr8;                                                       \
      gload16(kgl + (long)((KT)*64 + w*16 + row_)*64 + ((sc8 ^ (row_&7)) << 3),    \
              kd + i_*1024);                                                       \
    }                                                                              \
    if (w > 0) {                                                                   \
      char* vd = smem + 16384 + (BI)*6144 + (w-1)*2048;                            \
      _Pragma("unroll")                                                            \
      for (int i_ = 0; i_ < 2; ++i_) {                                             \
        int row_ = i_*8 + sr8;                                                     \
        gload16(vgl + (long)((w-1)*16 + row_)*2048 + (KT)*64 +                     \
                ((sc8 ^ (row_&7)) << 3), vd + i_*1024);                            \
      }                                                                            \
    }                                                                              \
  } while (0)

  STAGE_PR(0, prA); STAGE_KV(0, 0);
  STAGE_PR(1, prB); STAGE_KV(1, 1);

  float m = -1e30f, ssum = 0.f;
  f32x4 o0 = {0,0,0,0}, o1 = {0,0,0,0}, o2 = {0,0,0,0};

  #define BODY(T, PRBUF, PAR) do {                                                \
    if ((T) == 31)   { asm volatile("s_waitcnt vmcnt(0)" ::: "memory"); }          \
    else if (w == 0) { asm volatile("s_waitcnt vmcnt(6)" ::: "memory"); }          \
    else             { asm volatile("s_waitcnt vmcnt(8)" ::: "memory"); }          \
    __builtin_amdgcn_s_barrier();                                                  \
    FENCE;                                                                         \
    const char* kb = smem + (PAR)*8192;                                            \
    const char* vb = smem + 16384 + (PAR)*6144;                                    \
    f32x4 s[4];                                                                    \
    _Pragma("unroll")                                                              \
    for (int mf = 0; mf < 4; ++mf) {                                               \
      const int kr = mf*16 + q;                                                    \
      short8 ka = *(const short8*)(kb + kr*128 + ((g       ^ (q&7)) << 4));        \
      short8 kc = *(const short8*)(kb + kr*128 + (((g + 4) ^ (q&7)) << 4));        \
      s[mf] = MFMA(ka, qf0, PRBUF[mf]);                                            \
      s[mf] = MFMA(kc, qf1, s[mf]);                                                \
    }                                                                              \
    float tmax = -3e38f;                                                           \
    _Pragma("unroll")                                                              \
    for (int mf = 0; mf < 4; ++mf)                                                 \
      tmax = fmaxf(tmax, fmaxf(fmaxf(s[mf][0], s[mf][1]), fmaxf(s[mf][2], s[mf][3])));\
    tmax = fmaxf(tmax, __shfl_xor(tmax, 16));                                      \
    tmax = fmaxf(tmax, __shfl_xor(tmax, 32));                                      \
    float mnew = fmaxf(m, tmax);                                                   \
    float alpha = exp2f((m - mnew) * LOG2E);                                       \
    m = mnew;                                                                      \
    float mL = mnew * LOG2E;                                                       \
    float psum = 0.f;                                                              \
    unsigned pk0[4], pk1[4];                                                       \
    _Pragma("unroll")                                                              \
    for (int mf = 0; mf < 4; ++mf) {                                               \
      float p0 = exp2f(fmaf(s[mf][0], LOG2E, -mL));                                \
      float p1 = exp2f(fmaf(s[mf][1], LOG2E, -mL));                                \
      float p2 = exp2f(fmaf(s[mf][2], LOG2E, -mL));                                \
      float p3 = exp2f(fmaf(s[mf][3], LOG2E, -mL));                                \
      psum += (p0 + p1) + (p2 + p3);                                               \
      pk0[mf] = cvtpk(p0, p1);                                                     \
      pk1[mf] = cvtpk(p2, p3);                                                     \
    }                                                                              \
    ssum = ssum * alpha + psum;                                                    \
    o0 *= alpha; o1 *= alpha; o2 *= alpha;                                         \
    _Pragma("unroll")                                                              \
    for (int mf = 0; mf < 4; ++mf) {                                               \
      uint2 pv_; pv_.x = pk0[mf]; pv_.y = pk1[mf];                                 \
      *(uint2*)(pl + ((mf*8 + g*2) ^ sx)) = pv_;                                   \
    }                                                                              \
    asm volatile("s_waitcnt lgkmcnt(0)" ::: "memory");                             \
    __builtin_amdgcn_sched_barrier(0);                                             \
    _Pragma("unroll")                                                              \
    for (int ks = 0; ks < 2; ++ks) {                                               \
      union { uint4 u4; short8 v; } pf;                                            \
      pf.u4 = *(const uint4*)(pl + ((ks*16 + g*4) ^ sx));                          \
      const int vc = ((ks*4 + g) ^ (q & 7)) << 4;                                  \
      short8 v0 = *(const short8*)(vb + (q)*128      + vc);                        \
      short8 v1 = *(const short8*)(vb + (16 + q)*128 + vc);                        \
      short8 v2 = *(const short8*)(vb + (32 + q)*128 + vc);                        \
      o0 = MFMA(v0, pf.v, o0);                                                     \
      o1 = MFMA(v1, pf.v, o1);                                                     \
      o2 = MFMA(v2, pf.v, o2);                                                     \
    }                                                                              \
    FENCE;                                                                         \
    __builtin_amdgcn_s_barrier();                                                  \
    FENCE;                                                                         \
    if ((T) < 30) { STAGE_PR((T)+2, PRBUF); STAGE_KV((T)+2, PAR); }                \
    __builtin_amdgcn_sched_barrier(0);                                             \
  } while (0)

  for (int t = 0; t < 32; t += 2) {
    BODY(t,     prA, 0);
    BODY(t + 1, prB, 1);
  }
  #undef BODY
  #undef STAGE_PR
  #undef STAGE_KV

  ssum += __shfl_xor(ssum, 16);
  ssum += __shfl_xor(ssum, 32);
  float rinv = 1.f / ssum;
  const long nbase = (long)qrow * 768 + h * 48;
  #pragma unroll
  for (int r = 0; r < 3; ++r) {
    f32x4 ov = (r == 0) ? o0 : ((r == 1) ? o1 : o2);
    int c = r * 16 + g * 4;
    us4 gs = *(const us4*)(gsig + nbase + c);
    us4 ou;
    #pragma unroll
    for (int j = 0; j < 4; ++j) ou[j] = f2bf(ov[j] * rinv * bf2f(gs[j]));
    *(us4*)(wg + nbase + c) = ou;
  }
}

extern "C" void kernel_launch(void* const* d_in, const int* in_sizes, int n_in,
                              void* d_out, int out_size, void* d_ws, size_t ws_size,
                              hipStream_t stream) {
  const float* x       = (const float*)d_in[0];
  const float* mask    = (const float*)d_in[1];
  const float* pair    = (const float*)d_in[2];
  const float* sc      = (const float*)d_in[3];
  const float* q_w     = (const float*)d_in[4];
  const float* q_b     = (const float*)d_in[5];
  const float* k_w     = (const float*)d_in[6];
  const float* v_w     = (const float*)d_in[7];
  const float* g_w     = (const float*)d_in[8];
  const float* slw     = (const float*)d_in[9];
  const float* scale_w = (const float*)d_in[10];
  const float* scale_b = (const float*)d_in[11];
  const float* bias_w  = (const float*)d_in[12];
  const float* t2_w    = (const float*)d_in[13];
  const float* az_w    = (const float*)d_in[14];
  const float* az_b    = (const float*)d_in[15];
  float* out = (float*)d_out;
  char* ws = (char*)d_ws;

  u16*   Wsb   = (u16*)  (ws + 0);
  u16*   Waz   = (u16*)  (ws + 1179648);
  u16*   Wqkvg = (u16*)  (ws + 1769472);
  u16*   Wt2   = (u16*)  (ws + 6488064);
  float* xn    = (float*)(ws + 7667712);
  u16*   sc_bf = (u16*)  (ws + 13959168);
  u16*   scr_bf= (u16*)  (ws + 15532032);
  u16*   wg    = (u16*)  (ws + 13959168);   // reuse (sc dead after gemm_pair/ada)
  float* mb    = (float*)(ws + 17104896);
  float* Y1    = (float*)(ws + 17113088);
  u16*   qpad  = (u16*)  (ws + 17113088);   // reuse Y1 (dead after ada)
  u16*   kpad  = (u16*)  (ws + 21307392);
  float* Yaz   = (float*)(ws + 29696000);
  u16*   xm    = (u16*)  (ws + 35987456);
  float* azsig = (float*)(ws + 39133184);
  u16*   vt    = (u16*)  (ws + 70590464);
  u16*   gsig  = (u16*)  (ws + 73736192);

  prep_fused<<<7841, 256, 0, stream>>>(x, sc, slw, mask, xn, sc_bf, scr_bf, mb,
                                       scale_w, bias_w, az_w, q_w, k_w, v_w, g_w, t2_w,
                                       Wsb, Waz, Wqkvg, Wt2);
  gemm_pair64<<<dim3(32, 36), 256, 0, stream>>>(sc_bf, Wsb, Y1, scr_bf, Waz, Yaz);
  ada_kernel<<<1536, 256, 0, stream>>>(Y1, Yaz, xn, scale_b, az_b, xm, azsig);
  gemm_qkvg64<<<dim3(32, 49), 256, 0, stream>>>(xm, Wqkvg, q_b, mb, qpad, kpad, vt, gsig);
  attn_kernel<<<512, 256, 0, stream>>>(qpad, kpad, vt, pair, gsig, wg);
  gemm_az64<<<dim3(32, 12), 256, 0, stream>>>(wg, Wt2, azsig, out, 768, 768);
}